// Round 2
// baseline (928.643 us; speedup 1.0000x reference)
//
#include <hip/hip_runtime.h>

// UniformShardedEmbeddingBags: per-table embedding bag, sum pooling.
// weights: [E=200000, T=16, D=64] fp32 — row (e,t) is a contiguous 256 B block
//          at byte offset e*4096 + t*256 (256 B aligned).
// indices: [B=4096, T=16, L=20] int32
// out:     [B, T, D] fp32
//
// Shape: ONE WAVE PER BAG. The 20 indices of a bag are wave-uniform ->
// scalar (s_load) index fetch through the constant cache; each weights row
// gather is a single 256 B segment (64 lanes x 4 B) with an SGPR base.

constexpr int E = 200000;
constexpr int T = 16;
constexpr int D = 64;
constexpr int B = 4096;
constexpr int L = 20;

__global__ __launch_bounds__(256) void embed_bag_kernel(
    const float* __restrict__ w,      // [E, T, D]
    const int* __restrict__ idx,      // [B, T, L]
    float* __restrict__ out)          // [B, T, D]
{
    // Force wave-uniformity so the compiler scalarizes the index loads.
    const int wave = __builtin_amdgcn_readfirstlane(
        (blockIdx.x * blockDim.x + threadIdx.x) >> 6);   // = bag id in [0, B*T)
    const int lane = threadIdx.x & 63;

    const int t = wave & (T - 1);                 // bag = b*T + t
    const int* bag_idx = idx + wave * L;          // uniform pointer -> s_load
    const float* wt = w + t * D;                  // fold t*256B into the base

    float acc = 0.f;
#pragma unroll
    for (int l = 0; l < L; ++l) {
        const int e = bag_idx[l];                 // SGPR
        // uniform base + lane*4B: one 256 B segment per instruction
        acc += wt[(long long)e * (T * D) + lane];
    }

    out[wave * D + lane] = acc;                   // coalesced 256 B store/wave
}

extern "C" void kernel_launch(void* const* d_in, const int* in_sizes, int n_in,
                              void* d_out, int out_size, void* d_ws, size_t ws_size,
                              hipStream_t stream) {
    const float* w = (const float*)d_in[0];
    const int* idx = (const int*)d_in[1];
    float* out = (float*)d_out;

    // One wave (64 lanes) per bag; 4 waves per 256-thread block.
    const int n_bags = B * T;                      // 65536
    const int block = 256;
    const int grid = n_bags / (block / 64);        // 16384
    embed_bag_kernel<<<grid, block, 0, stream>>>(w, idx, out);
}